// Round 9
// baseline (519.772 us; speedup 1.0000x reference)
//
#include <hip/hip_runtime.h>
#include <hip/hip_bf16.h>

#define NNODES 10000
#define TLEN 24
#define INDIM 16
#define HID 128
#define GDIM 512   // 4*HID (LSTM gates) == HEADS*HID (GAT)

typedef __hip_bfloat16 bf16;
typedef short v8s __attribute__((ext_vector_type(8)));
typedef float v4f __attribute__((ext_vector_type(4)));

__device__ inline float u2f(unsigned u){ return __uint_as_float(u); }
__device__ inline float frcp(float x){ return __builtin_amdgcn_rcpf(x); }

__device__ inline void unpack8(uint4 v, float* f){
  f[0]=u2f(v.x<<16); f[1]=u2f(v.x&0xFFFF0000u);
  f[2]=u2f(v.y<<16); f[3]=u2f(v.y&0xFFFF0000u);
  f[4]=u2f(v.z<<16); f[5]=u2f(v.z&0xFFFF0000u);
  f[6]=u2f(v.w<<16); f[7]=u2f(v.w&0xFFFF0000u);
}

// ---------------------------------------------------------------------------
// Convert 11 f32 weight matrices (MFMA B-operands) to bf16; zero CSR degrees.
// Order: wih0,whh0,wih1,whh1, wl0,wr0,pw0, wl1,wr1,pw1 (65536 ea), mow0 (16384).
// Uniform source select on blockIdx.x>>8 (no runtime-indexed pointer array).
// ---------------------------------------------------------------------------
__global__ __launch_bounds__(256) void conv_w_k(
    const float* s0, const float* s1, const float* s2, const float* s3,
    const float* s4, const float* s5, const float* s6, const float* s7,
    const float* s8, const float* s9, const float* s10,
    bf16* __restrict__ dst, int* __restrict__ deg)
{
  int idx = blockIdx.x*256 + threadIdx.x;
  if (idx < NNODES) deg[idx] = 0;
  if (idx >= 671744) return;
  int b = blockIdx.x >> 8;        // uniform per block: 0..9 chunks, 10 = mow0
  const float* s;
  if      (b == 0) s = s0;
  else if (b == 1) s = s1;
  else if (b == 2) s = s2;
  else if (b == 3) s = s3;
  else if (b == 4) s = s4;
  else if (b == 5) s = s5;
  else if (b == 6) s = s6;
  else if (b == 7) s = s7;
  else if (b == 8) s = s8;
  else if (b == 9) s = s9;
  else             s = s10;
  dst[idx] = __float2bfloat16(s[idx - b*65536]);
}

// ---------------------------------------------------------------------------
// Prep + MERGED deg-count (deg zeroed by conv_w_k, stream-ordered before us):
// blocks 0..7: Wp fold. block 8: bp, bsum, gblr. 9..: degree atomics.
// ---------------------------------------------------------------------------
__global__ __launch_bounds__(256) void prep_w_k(
    const float* __restrict__ miw0, const float* __restrict__ mib0,
    const float* __restrict__ miw1, const float* __restrict__ mib1,
    const float* __restrict__ bih0, const float* __restrict__ bhh0,
    const float* __restrict__ bih1, const float* __restrict__ bhh1,
    const float* __restrict__ bl0, const float* __restrict__ br0,
    const float* __restrict__ bl1, const float* __restrict__ br1,
    float* __restrict__ Wp, float* __restrict__ bp,
    float* __restrict__ bsum, float* __restrict__ gblr,
    const int* __restrict__ dst, int* __restrict__ deg, int E)
{
  int t = threadIdx.x;
  int b = blockIdx.x;
  if (b >= 9){
    int e = (b-9)*256 + t;
    if (e < E){
      unsigned d = (unsigned)dst[e];
      if (d < (unsigned)NNODES) atomicAdd(&deg[d], 1);
    }
    return;
  }
  if (b < 8){
    int idx = b*256 + t;          // < 2048 = HID*INDIM
    int j = idx >> 4, d = idx & 15;
    float s = 0.f;
    for (int k=0;k<HID;k++) s += miw1[j*HID+k] * miw0[k*INDIM+d];
    Wp[idx] = s;
    return;
  }
  // block 8: bp + bsum + gblr
  if (t < HID){
    float s = mib1[t];
    for (int k=0;k<HID;k++) s += miw1[t*HID+k] * mib0[k];
    bp[t] = s;
  }
  for (int i = t; i < GDIM; i += 256){
    bsum[i]        = bih0[i] + bhh0[i];
    bsum[GDIM + i] = bih1[i] + bhh1[i];
  }
  for (int i = t; i < GDIM; i += 256){
    gblr[i]          = bl0[i];
    gblr[GDIM + i]   = br0[i];
    gblr[1024 + i]   = bl1[i];
    gblr[1536 + i]   = br1[i];
  }
}

// ---------------------------------------------------------------------------
// PARALLEL exclusive scan: 1024 threads x 10 elems, wave shfl-scan + 16
// wave-sums. Integer-exact => CSR identical.
// ---------------------------------------------------------------------------
__global__ __launch_bounds__(1024) void scan_k(
    const int* __restrict__ deg, int* __restrict__ offs,
    int* __restrict__ cursor, int n)
{
  __shared__ int wsum[16];
  __shared__ int wpre[16];
  const int t = threadIdx.x;
  const int lane = t & 63, wv = t >> 6;
  const int lo = t*10;
  int loc[10];
  int s = 0;
  #pragma unroll
  for (int i=0;i<10;i++){
    int idx = lo + i;
    int d = (idx < n) ? deg[idx] : 0;
    loc[i] = d; s += d;
  }
  int sc = s;
  #pragma unroll
  for (int off=1; off<64; off<<=1){
    int u = __shfl_up(sc, off);
    if (lane >= off) sc += u;
  }
  if (lane == 63) wsum[wv] = sc;
  __syncthreads();
  if (t == 0){
    int run = 0;
    #pragma unroll
    for (int i=0;i<16;i++){ wpre[i] = run; run += wsum[i]; }
    offs[n] = run;
  }
  __syncthreads();
  int run = wpre[wv] + (sc - s);   // exclusive prefix for this thread
  #pragma unroll
  for (int i=0;i<10;i++){
    int idx = lo + i;
    if (idx < n){ offs[idx] = run; cursor[idx] = run; run += loc[i]; }
  }
}

// ---------------------------------------------------------------------------
// LSTM layer body (proven M=48 structure, merged 8-trans epilogue).
// Layer 0 (WRITE_ALL=1) writes h(t) in-place over Xio; layer 1 (WRITE_ALL=0)
// reads them back (same block, same CU, L1/L2-hot) and writes final h to out.
// ---------------------------------------------------------------------------
template<int WRITE_ALL>
__device__ __forceinline__ void lstm_layer(
    bf16* Xio, const bf16* __restrict__ Wih, const bf16* __restrict__ Whh,
    const float* __restrict__ bias, bf16* __restrict__ out,
    bf16* hs, bf16* xs, int m0)
{
  const int tid = threadIdx.x;
  const int lane = tid & 63, w = tid >> 6;
  const int r16 = lane & 15, quad = lane >> 4;
  const int HB = 48*136;   // one buffer

  v8s wbi[4][4], wbh[4][4];
  #pragma unroll
  for (int g=0; g<4; g++)
    #pragma unroll
    for (int kc=0; kc<4; kc++){
      size_t o = (size_t)(g*HID + w*16 + r16)*HID + kc*32 + quad*8;
      wbi[g][kc] = *(const v8s*)(Wih + o);
      wbh[g][kc] = *(const v8s*)(Whh + o);
    }
  float bg[4];
  #pragma unroll
  for (int g=0; g<4; g++) bg[g] = bias[g*HID + w*16 + r16];

  const int row0 = tid >> 4;                 // rows 0..31
  const int c8   = (tid & 15) * 8;
  const int row1 = 32 + (tid >> 4);          // rows 32..47 (tid < 256 only)
  const int gr0 = m0 + row0;
  const int gr1 = m0 + row1;
  const int gr0c = gr0 < NNODES ? gr0 : NNODES-1;
  const int gr1c = gr1 < NNODES ? gr1 : NNODES-1;
  const bf16* ldp0 = Xio + (size_t)gr0c*HID + c8;
  const bf16* ldp1 = Xio + (size_t)gr1c*HID + c8;
  bf16* stp0 = Xio + (size_t)gr0*HID + c8;
  bf16* stp1 = Xio + (size_t)gr1*HID + c8;
  const size_t TS = (size_t)NNODES*HID;

  for (int i = tid; i < 816; i += 512)
    *(uint4*)((char*)hs + i*16) = make_uint4(0,0,0,0);   // zero hs[0]

  {
    uint4 a = *(const uint4*)ldp0;
    *(uint4*)(xs + row0*136 + c8) = a;
    if (tid < 256){
      uint4 b = *(const uint4*)ldp1;
      *(uint4*)(xs + row1*136 + c8) = b;
    }
  }
  __syncthreads();

  float c[3][4];
  #pragma unroll
  for (int tl=0; tl<3; tl++)
    #pragma unroll
    for (int r=0; r<4; r++) c[tl][r] = 0.f;

  const int fb = r16*136 + quad*8;   // frag base within a 16-row tile

  #pragma unroll 1
  for (int t=0; t<TLEN; t++){
    const int cur = t & 1, nxt = cur ^ 1;
    const bf16* xrd = xs + cur*HB;
    const bf16* hrd = hs + cur*HB;
    bf16* hwr = hs + nxt*HB;

    const int tn = (t+1 < TLEN) ? t+1 : TLEN-1;
    uint4 xa = *(const uint4*)(ldp0 + (size_t)tn*TS);
    uint4 xb;
    if (tid < 256) xb = *(const uint4*)(ldp1 + (size_t)tn*TS);

    #pragma unroll
    for (int tl=0; tl<3; tl++){
      v4f acc[4];
      #pragma unroll
      for (int g=0; g<4; g++) acc[g] = (v4f)0.f;

      #pragma unroll
      for (int kc=0; kc<4; kc++){
        v8s av = *(const v8s*)(xrd + tl*2176 + fb + kc*32);
        #pragma unroll
        for (int g=0; g<4; g++)
          acc[g] = __builtin_amdgcn_mfma_f32_16x16x32_bf16(av, wbi[g][kc], acc[g], 0, 0, 0);
      }
      #pragma unroll
      for (int kc=0; kc<4; kc++){
        v8s hv = *(const v8s*)(hrd + tl*2176 + fb + kc*32);
        #pragma unroll
        for (int g=0; g<4; g++)
          acc[g] = __builtin_amdgcn_mfma_f32_16x16x32_bf16(hv, wbh[g][kc], acc[g], 0, 0, 0);
      }

      #pragma unroll
      for (int r=0; r<4; r++){
        float iv = acc[0][r] + bg[0];
        float fv = acc[1][r] + bg[1];
        float gv = acc[2][r] + bg[2];
        float ov = acc[3][r] + bg[3];
        float sf = frcp(1.f + __expf(-fv));
        float ei = __expf(-iv);
        float tg = __expf(-2.f*fabsf(gv));
        float itg = copysignf((1.f - tg)*frcp((1.f + ei)*(1.f + tg)), gv);
        float cn = sf*c[tl][r] + itg;
        c[tl][r] = cn;
        float eo = __expf(-ov);
        float tc = __expf(-2.f*fabsf(cn));
        float hh = copysignf((1.f - tc)*frcp((1.f + eo)*(1.f + tc)), cn);
        hwr[(tl*16 + quad*4 + r)*136 + w*16 + r16] = __float2bfloat16(hh);
      }
    }

    *(uint4*)(xs + nxt*HB + row0*136 + c8) = xa;
    if (tid < 256) *(uint4*)(xs + nxt*HB + row1*136 + c8) = xb;

    __syncthreads();

    if (WRITE_ALL){
      uint4 h0 = *(const uint4*)(hwr + row0*136 + c8);
      if (gr0 < NNODES) *(uint4*)(stp0 + (size_t)t*TS) = h0;
      if (tid < 256){
        uint4 h1v = *(const uint4*)(hwr + row1*136 + c8);
        if (gr1 < NNODES) *(uint4*)(stp1 + (size_t)t*TS) = h1v;
      }
    }
  }

  if (!WRITE_ALL){
    const bf16* hf = hs + (TLEN & 1)*HB;
    uint4 h0 = *(const uint4*)(hf + row0*136 + c8);
    if (gr0 < NNODES) *(uint4*)(out + (size_t)gr0*HID + c8) = h0;
    if (tid < 256){
      uint4 h1v = *(const uint4*)(hf + row1*136 + c8);
      if (gr1 < NNODES) *(uint4*)(out + (size_t)gr1*HID + c8) = h1v;
    }
  }
}

// ---------------------------------------------------------------------------
// Fused MLP-in PROLOGUE + 2-layer LSTM, one dispatch.
// Prologue (before any MFMA weights are loaded -> no register-pressure
// impact on the recurrence): each block computes X0 rows [m0,m0+48) for all
// 24 t with the EXACT mlp_in FMA expression/order (bit-identical values),
// writing to the same X0 locations; the recurrence then re-reads them
// L1/L2-hot (same block, same CU). Also performs the CSR fill (2 edges per
// thread) — the old mlp_in_k kernel disappears entirely.
// Prologue LDS scratch (Wp x-rows dbuf, 6 KB) lives inside the hs region,
// which lstm_layer zeroes afterwards.
// ---------------------------------------------------------------------------
__global__ __launch_bounds__(512) void lstm_f2(
    bf16* X0, const bf16* __restrict__ wih0, const bf16* __restrict__ whh0,
    const bf16* __restrict__ wih1, const bf16* __restrict__ whh1,
    const float* __restrict__ bsum, bf16* __restrict__ zf,
    const float* __restrict__ x, const float* __restrict__ Wp,
    const float* __restrict__ bp,
    const int* __restrict__ srcp, const int* __restrict__ dstp,
    int* __restrict__ curs, int* __restrict__ srcs, int E)
{
  __shared__ __align__(16) bf16 hs[2][48*136];
  __shared__ __align__(16) bf16 xs[2][48*136];
  const int tid = threadIdx.x;
  const int m0 = blockIdx.x*48;

  // ================= PROLOGUE =================
  {
    // CSR fill: 209*512 = 107008 threads, 2 strided passes cover E
    for (int e = blockIdx.x*512 + tid; e < E; e += gridDim.x*512){
      unsigned d = (unsigned)dstp[e];
      if (d < (unsigned)NNODES){
        int p = atomicAdd(&curs[d], 1);
        unsigned sv = (unsigned)srcp[e];
        srcs[p] = (sv < (unsigned)NNODES) ? (int)sv : 0;
      }
    }

    float* xrow = (float*)&hs[0][0];       // [2][48][16] f32 = 6144 B dbuf
    const int j  = tid & 127;
    const int rq = tid >> 7;               // 0..3 -> rows rq*12 .. rq*12+11
    const float* wr = Wp + j*INDIM;
    float4 w0 = *(const float4*)(wr);
    float4 w1 = *(const float4*)(wr + 4);
    float4 w2 = *(const float4*)(wr + 8);
    float4 w3 = *(const float4*)(wr + 12);
    float bj = bp[j];

    // stage x(t=0): threads 0..191, r=tid>>2, kq=tid&3
    if (tid < 192){
      int r = tid >> 2, kq = tid & 3;
      int n = m0 + r; if (n >= NNODES) n = NNODES-1;
      *(float4*)(xrow + r*16 + kq*4) =
          *(const float4*)(x + ((size_t)n*TLEN + 0)*INDIM + kq*4);
    }
    __syncthreads();

    for (int t=0; t<TLEN; t++){
      const int cur = t & 1, nxt = cur ^ 1;
      float4 xa;
      if (tid < 192 && t+1 < TLEN){
        int r = tid >> 2, kq = tid & 3;
        int n = m0 + r; if (n >= NNODES) n = NNODES-1;
        xa = *(const float4*)(x + ((size_t)n*TLEN + (t+1))*INDIM + kq*4);
      }
      const float* xb = xrow + cur*768;
      bf16* dst = X0 + (size_t)t*NNODES*HID;
      #pragma unroll 2
      for (int rr=0; rr<12; rr++){
        int r = rq*12 + rr;
        int n = m0 + r;
        const float* a = xb + r*16;          // wave-uniform -> LDS broadcast
        float4 a0 = *(const float4*)(a);
        float4 a1 = *(const float4*)(a + 4);
        float4 a2 = *(const float4*)(a + 8);
        float4 a3 = *(const float4*)(a + 12);
        float s = bj
          + a0.x*w0.x + a0.y*w0.y + a0.z*w0.z + a0.w*w0.w
          + a1.x*w1.x + a1.y*w1.y + a1.z*w1.z + a1.w*w1.w
          + a2.x*w2.x + a2.y*w2.y + a2.z*w2.z + a2.w*w2.w
          + a3.x*w3.x + a3.y*w3.y + a3.z*w3.z + a3.w*w3.w;
        s = s > 0.f ? s : 0.f;
        if (n < NNODES) dst[(size_t)n*HID + j] = __float2bfloat16(s);
      }
      if (tid < 192 && t+1 < TLEN){
        int r = tid >> 2, kq = tid & 3;
        *(float4*)(xrow + nxt*768 + r*16 + kq*4) = xa;
      }
      __syncthreads();   // xrow[nxt] ready; X0(t) stores drained at barrier
    }
  }
  // ================= RECURRENCE =================
  lstm_layer<1>(X0, wih0, whh0, bsum,        nullptr, &hs[0][0], &xs[0][0], m0);
  __syncthreads();   // drain layer-0 final writeback before hs/xs reuse
  lstm_layer<0>(X0, wih1, whh1, bsum + GDIM, zf,      &hs[0][0], &xs[0][0], m0);
}

// ---------------------------------------------------------------------------
// Generic bf16 GEMM: C[M,N] = act(A[M,K] @ B[N,K]^T + bias_f32[N]), bf16 out.
// (Proven 128x128 tile.)
// ---------------------------------------------------------------------------
template<int ACT>
__global__ __launch_bounds__(256) void gemm_bt(
    const bf16* __restrict__ A, const bf16* __restrict__ B,
    const float* __restrict__ bias, bf16* __restrict__ C,
    int M, int N, int K)
{
  __shared__ __align__(16) bf16 As[128*40];
  __shared__ __align__(16) bf16 Bs[128*40];
  const int tid = threadIdx.x;
  const int m0 = blockIdx.x*128, n0 = blockIdx.y*128;
  const int lane = tid & 63, wave = tid >> 6;
  const int r16 = lane & 15, quad = lane >> 4;

  v4f acc[2][8];
  #pragma unroll
  for (int a=0;a<2;a++)
    #pragma unroll
    for (int b=0;b<8;b++) acc[a][b] = (v4f)0.f;

  for (int k0=0; k0<K; k0+=32){
    #pragma unroll
    for (int i=0;i<2;i++){
      int li = tid + i*256;
      int row = li >> 2, q4 = li & 3;
      uint4 va = make_uint4(0,0,0,0);
      int gm = m0 + row;
      if (gm < M) va = *(const uint4*)(A + (size_t)gm*K + k0 + q4*8);
      *(uint4*)(As + row*40 + q4*8) = va;
      uint4 vb = make_uint4(0,0,0,0);
      int gn = n0 + row;
      if (gn < N) vb = *(const uint4*)(B + (size_t)gn*K + k0 + q4*8);
      *(uint4*)(Bs + row*40 + q4*8) = vb;
    }
    __syncthreads();
    v8s av[2], bv[8];
    #pragma unroll
    for (int mi=0;mi<2;mi++)
      av[mi] = *(const v8s*)(As + (wave*32 + mi*16 + r16)*40 + quad*8);
    #pragma unroll
    for (int ni=0;ni<8;ni++)
      bv[ni] = *(const v8s*)(Bs + (ni*16 + r16)*40 + quad*8);
    #pragma unroll
    for (int mi=0;mi<2;mi++)
      #pragma unroll
      for (int ni=0;ni<8;ni++)
        acc[mi][ni] = __builtin_amdgcn_mfma_f32_16x16x32_bf16(av[mi], bv[ni], acc[mi][ni], 0, 0, 0);
    __syncthreads();
  }

  #pragma unroll
  for (int mi=0;mi<2;mi++){
    #pragma unroll
    for (int r=0;r<4;r++){
      int row = m0 + wave*32 + mi*16 + quad*4 + r;
      if (row >= M) continue;
      #pragma unroll
      for (int ni=0;ni<8;ni++){
        int col = n0 + ni*16 + r16;
        float v = acc[mi][ni][r] + bias[col];
        if (ACT == 1) v = v > 0.f ? v : 0.f;
        C[(size_t)row*N + col] = __float2bfloat16(v);
      }
    }
  }
}

// ---------------------------------------------------------------------------
// 64-row-tile GEMM for N=128 outputs (GAT projection).
// ---------------------------------------------------------------------------
template<int ACT>
__global__ __launch_bounds__(256) void gemm_bt64(
    const bf16* __restrict__ A, const bf16* __restrict__ B,
    const float* __restrict__ bias, bf16* __restrict__ C,
    int M, int K)   // N == 128
{
  __shared__ __align__(16) bf16 As[64*40];
  __shared__ __align__(16) bf16 Bs[128*40];
  const int tid = threadIdx.x;
  const int m0 = blockIdx.x*64;
  const int lane = tid & 63, wave = tid >> 6;
  const int r16 = lane & 15, quad = lane >> 4;

  v4f acc[8];
  #pragma unroll
  for (int b=0;b<8;b++) acc[b] = (v4f)0.f;

  for (int k0=0; k0<K; k0+=32){
    {
      int row = tid >> 2, q4 = tid & 3;
      uint4 va = make_uint4(0,0,0,0);
      int gm = m0 + row;
      if (gm < M) va = *(const uint4*)(A + (size_t)gm*K + k0 + q4*8);
      *(uint4*)(As + row*40 + q4*8) = va;
    }
    #pragma unroll
    for (int i=0;i<2;i++){
      int li = tid + i*256;
      int row = li >> 2, q4 = li & 3;
      uint4 vb = *(const uint4*)(B + (size_t)row*K + k0 + q4*8);
      *(uint4*)(Bs + row*40 + q4*8) = vb;
    }
    __syncthreads();
    v8s av, bv[8];
    av = *(const v8s*)(As + (wave*16 + r16)*40 + quad*8);
    #pragma unroll
    for (int ni=0;ni<8;ni++)
      bv[ni] = *(const v8s*)(Bs + (ni*16 + r16)*40 + quad*8);
    #pragma unroll
    for (int ni=0;ni<8;ni++)
      acc[ni] = __builtin_amdgcn_mfma_f32_16x16x32_bf16(av, bv[ni], acc[ni], 0, 0, 0);
    __syncthreads();
  }

  #pragma unroll
  for (int r=0;r<4;r++){
    int row = m0 + wave*16 + quad*4 + r;
    if (row >= M) continue;
    #pragma unroll
    for (int ni=0;ni<8;ni++){
      int col = ni*16 + r16;
      float v = acc[ni][r] + bias[col];
      if (ACT == 1) v = v > 0.f ? v : 0.f;
      C[(size_t)row*HID + col] = __float2bfloat16(v);
    }
  }
}

// ---------------------------------------------------------------------------
// MLP-out FUSED: o0 = relu(z3 @ mow0^T + mob0) like gemm_bt64, o0 tile to
// LDS, then the final N=24 layer from LDS (same accumulation order).
// ---------------------------------------------------------------------------
__global__ __launch_bounds__(256) void mlp_out_fused_k(
    const bf16* __restrict__ A, const bf16* __restrict__ B,
    const float* __restrict__ bias, const float* __restrict__ w1,
    const float* __restrict__ b1, float* __restrict__ out, int M)
{
  __shared__ __align__(16) bf16 As[64*40];
  __shared__ __align__(16) bf16 Bs[128*40];
  __shared__ __align__(16) bf16 o0s[64*136];
  const int tid = threadIdx.x;
  const int m0 = blockIdx.x*64;
  const int lane = tid & 63, wave = tid >> 6;
  const int r16 = lane & 15, quad = lane >> 4;

  v4f acc[8];
  #pragma unroll
  for (int b=0;b<8;b++) acc[b] = (v4f)0.f;

  for (int k0=0; k0<HID; k0+=32){
    {
      int row = tid >> 2, q4 = tid & 3;
      uint4 va = make_uint4(0,0,0,0);
      int gm = m0 + row;
      if (gm < M) va = *(const uint4*)(A + (size_t)gm*HID + k0 + q4*8);
      *(uint4*)(As + row*40 + q4*8) = va;
    }
    #pragma unroll
    for (int i=0;i<2;i++){
      int li = tid + i*256;
      int row = li >> 2, q4 = li & 3;
      uint4 vb = *(const uint4*)(B + (size_t)row*HID + k0 + q4*8);
      *(uint4*)(Bs + row*40 + q4*8) = vb;
    }
    __syncthreads();
    v8s av, bv[8];
    av = *(const v8s*)(As + (wave*16 + r16)*40 + quad*8);
    #pragma unroll
    for (int ni=0;ni<8;ni++)
      bv[ni] = *(const v8s*)(Bs + (ni*16 + r16)*40 + quad*8);
    #pragma unroll
    for (int ni=0;ni<8;ni++)
      acc[ni] = __builtin_amdgcn_mfma_f32_16x16x32_bf16(av, bv[ni], acc[ni], 0, 0, 0);
    __syncthreads();
  }

  #pragma unroll
  for (int r=0;r<4;r++){
    int row = wave*16 + quad*4 + r;
    #pragma unroll
    for (int ni=0;ni<8;ni++){
      int col = ni*16 + r16;
      float v = acc[ni][r] + bias[col];
      v = v > 0.f ? v : 0.f;
      o0s[row*136 + col] = __float2bfloat16(v);
    }
  }
  __syncthreads();

  for (int idx = tid; idx < 64*24; idx += 256){
    int row = idx / 24, j = idx - row*24;
    if (m0 + row >= M) continue;
    const bf16* ar = o0s + row*136;
    const float* wr = w1 + j*HID;
    float s = b1[j];
    for (int k=0;k<HID;k+=8){
      float fa[8];
      unpack8(*(const uint4*)(ar+k), fa);
      float4 w0 = *(const float4*)(wr + k);
      float4 w1v = *(const float4*)(wr + k + 4);
      s += fa[0]*w0.x + fa[1]*w0.y + fa[2]*w0.z + fa[3]*w0.w
         + fa[4]*w1v.x + fa[5]*w1v.y + fa[6]*w1v.z + fa[7]*w1v.w;
    }
    out[(size_t)(m0+row)*24 + j] = s;
  }
}

// ---------------------------------------------------------------------------
// GATv2 online-softmax fused score+aggregate, distance-2 prefetch pipeline
// (order-identical math). 1 wave/dst node.
// ---------------------------------------------------------------------------
__global__ __launch_bounds__(256) void gat_onl(
    const int* __restrict__ offs, const int* __restrict__ srcs,
    const bf16* __restrict__ xc, const float* __restrict__ att,
    const float* __restrict__ gbias, bf16* __restrict__ agg)
{
  int d = blockIdx.x*4 + (threadIdx.x >> 6);
  if (d >= NNODES) return;
  int lane = threadIdx.x & 63;
  float fr[8];
  unpack8(*(const uint4*)(xc + (size_t)d*1024 + 512 + lane*8), fr);
  float4 a0 = *(const float4*)(att + lane*8);
  float4 a1 = *(const float4*)(att + lane*8 + 4);
  float fa[8] = {a0.x,a0.y,a0.z,a0.w,a1.x,a1.y,a1.z,a1.w};
  int i0 = offs[d], i1 = offs[d+1];

  float m = -3.4e38f, den = 0.f;
  float acc[8] = {0,0,0,0,0,0,0,0};

  if (i0 < i1){
    uint4 r0 = *(const uint4*)(xc + (size_t)srcs[i0]*1024 + lane*8);
    uint4 r1 = r0;
    if (i0+1 < i1) r1 = *(const uint4*)(xc + (size_t)srcs[i0+1]*1024 + lane*8);
    for (int i=i0; i<i1; i++){
      uint4 r2 = r1;
      if (i+2 < i1) r2 = *(const uint4*)(xc + (size_t)srcs[i+2]*1024 + lane*8);
      float fl[8];
      unpack8(r0, fl);
      float p = 0.f;
      #pragma unroll
      for (int q=0;q<8;q++){
        float v = fl[q] + fr[q];
        v = v > 0.f ? v : 0.2f*v;
        p += v*fa[q];
      }
      p += __shfl_xor(p, 1); p += __shfl_xor(p, 2);
      p += __shfl_xor(p, 4); p += __shfl_xor(p, 8);
      float mn = fmaxf(m, p);
      float corr = __expf(m - mn);
      float w = __expf(p - mn);
      den = den*corr + w;
      #pragma unroll
      for (int q=0;q<8;q++) acc[q] = acc[q]*corr + w*fl[q];
      m = mn;
      r0 = r1; r1 = r2;
    }
  }
  float r = 1.f/(den + 1e-16f);
  float4 b0 = *(const float4*)(gbias + lane*8);
  float4 b1 = *(const float4*)(gbias + lane*8 + 4);
  float fb[8] = {b0.x,b0.y,b0.z,b0.w,b1.x,b1.y,b1.z,b1.w};
  #pragma unroll
  for (int q=0;q<8;q++)
    agg[(size_t)d*GDIM + lane*8 + q] = __float2bfloat16(acc[q]*r + fb[q]);
}

// ---------------------------------------------------------------------------

extern "C" void kernel_launch(void* const* d_in, const int* in_sizes, int n_in,
                              void* d_out, int out_size, void* d_ws, size_t ws_size,
                              hipStream_t stream)
{
  const float* x   = (const float*)d_in[0];
  const int*   ei  = (const int*)d_in[1];
  const int E = in_sizes[1] / 2;
  const int* srcp = ei;
  const int* dstp = ei + E;

  const float* miw0 = (const float*)d_in[2];
  const float* mib0 = (const float*)d_in[3];
  const float* miw1 = (const float*)d_in[4];
  const float* mib1 = (const float*)d_in[5];
  const float* wih0 = (const float*)d_in[6];
  const float* whh0 = (const float*)d_in[7];
  const float* bih0 = (const float*)d_in[8];
  const float* bhh0 = (const float*)d_in[9];
  const float* wih1 = (const float*)d_in[10];
  const float* whh1 = (const float*)d_in[11];
  const float* bih1 = (const float*)d_in[12];
  const float* bhh1 = (const float*)d_in[13];
  const float* g_wl[2]   = {(const float*)d_in[14], (const float*)d_in[22]};
  const float* g_bl[2]   = {(const float*)d_in[15], (const float*)d_in[23]};
  const float* g_wr[2]   = {(const float*)d_in[16], (const float*)d_in[24]};
  const float* g_br[2]   = {(const float*)d_in[17], (const float*)d_in[25]};
  const float* g_att[2]  = {(const float*)d_in[18], (const float*)d_in[26]};
  const float* g_bias[2] = {(const float*)d_in[19], (const float*)d_in[27]};
  const float* g_pw[2]   = {(const float*)d_in[20], (const float*)d_in[28]};
  const float* g_pb[2]   = {(const float*)d_in[21], (const float*)d_in[29]};
  const float* mow0 = (const float*)d_in[30];
  const float* mob0 = (const float*)d_in[31];
  const float* mow1 = (const float*)d_in[32];
  const float* mob1 = (const float*)d_in[33];
  (void)n_in; (void)out_size; (void)ws_size;

  // ---- workspace layout ----
  char* base = (char*)d_ws;
  size_t off = 0;
  auto carve = [&](size_t n)->char*{
    char* p = base + off;
    off = (off + n + 255) & ~(size_t)255;
    return p;
  };
  char*  X0r = carve((size_t)TLEN*NNODES*HID*2);   // 61,440,000
  bf16*  zf  = (bf16*)carve((size_t)NNODES*HID*2);
  float* Wp  = (float*)carve(HID*INDIM*4);
  float* bp  = (float*)carve(HID*4);
  float* bsum= (float*)carve(2*GDIM*4);
  float* gblr= (float*)carve(2*1024*4);
  bf16*  wbf = (bf16*)carve((size_t)671744*2);
  int*   offsb = (int*)carve((size_t)(NNODES+1)*4);
  int*   curs  = (int*)carve((size_t)NNODES*4);
  int*   srcs  = (int*)carve((size_t)E*4);
  int*   deg   = (int*)carve((size_t)NNODES*4);
  bf16*  agg   = (bf16*)carve((size_t)NNODES*GDIM*2);

  // wbf sub-pointers (conv_w_k chunk order)
  const bf16* wih0b = wbf + 0;
  const bf16* whh0b = wbf + 65536;
  const bf16* wih1b = wbf + 131072;
  const bf16* whh1b = wbf + 196608;
  const bf16* wlr0b = wbf + 262144;   // wl0|wr0 contiguous [1024,128]
  const bf16* pw0b  = wbf + 393216;
  const bf16* wlr1b = wbf + 458752;   // wl1|wr1 contiguous
  const bf16* pw1b  = wbf + 589824;
  const bf16* mow0b = wbf + 655360;
  const bf16* wlrb[2] = {wlr0b, wlr1b};
  const bf16* pwb[2]  = {pw0b, pw1b};

  // X0 region aliases (holds X0/h1 during LSTM, dead after; then xc/z2/z3)
  bf16* X0 = (bf16*)X0r;
  bf16* xc = (bf16*)X0r;                      // [10000,1024] = xl|xr
  bf16* z2 = (bf16*)(X0r + 20480000);
  bf16* z3 = (bf16*)(X0r + 23040000);

  // ---- prep: conv (zeroes deg) -> prep(+deg count) -> scan ----
  conv_w_k<<<2624, 256, 0, stream>>>(wih0, whh0, wih1, whh1,
                                     g_wl[0], g_wr[0], g_pw[0],
                                     g_wl[1], g_wr[1], g_pw[1], mow0, wbf, deg);
  prep_w_k<<<9 + (E+255)/256, 256, 0, stream>>>(miw0, mib0, miw1, mib1,
                                  bih0, bhh0, bih1, bhh1,
                                  g_bl[0], g_br[0], g_bl[1], g_br[1],
                                  Wp, bp, bsum, gblr, dstp, deg, E);
  scan_k<<<1, 1024, 0, stream>>>(deg, offsb, curs, NNODES);

  // ---- LSTM (with MLP-in prologue + CSR fill), one dispatch ----
  const int NBL48 = (NNODES + 47) / 48;   // 209
  lstm_f2<<<NBL48, 512, 0, stream>>>(X0, wih0b, whh0b, wih1b, whh1b, bsum, zf,
                                     x, Wp, bp, srcp, dstp, curs, srcs, E);

  // ---- GAT layers (R7's proven separate kernels) ----
  const bf16* zin = zf;
  bf16* zouts[2] = {z2, z3};
  const int NB64 = (NNODES + 63) / 64;   // 157 blocks
  for (int l=0; l<2; l++){
    gemm_bt<0><<<dim3(79,8), 256, 0, stream>>>(zin, wlrb[l], gblr + l*1024, xc, NNODES, 1024, HID);
    gat_onl<<<(NNODES+3)/4, 256, 0, stream>>>(offsb, srcs, xc, g_att[l], g_bias[l], agg);
    gemm_bt64<1><<<NB64, 256, 0, stream>>>(agg, pwb[l], g_pb[l], zouts[l], NNODES, GDIM);
    zin = zouts[l];
  }

  // ---- MLP out (fused GEMM + final layer) ----
  mlp_out_fused_k<<<NB64, 256, 0, stream>>>(z3, mow0b, mob0, mow1, mob1,
                                            (float*)d_out, NNODES);
}

// Round 10
// 500.921 us; speedup vs baseline: 1.0376x; 1.0376x over previous
//
#include <hip/hip_runtime.h>
#include <hip/hip_bf16.h>

#define NNODES 10000
#define TLEN 24
#define INDIM 16
#define HID 128
#define GDIM 512   // 4*HID (LSTM gates) == HEADS*HID (GAT)

typedef __hip_bfloat16 bf16;
typedef short v8s __attribute__((ext_vector_type(8)));
typedef float v4f __attribute__((ext_vector_type(4)));

__device__ inline float u2f(unsigned u){ return __uint_as_float(u); }
__device__ inline float frcp(float x){ return __builtin_amdgcn_rcpf(x); }

__device__ inline void unpack8(uint4 v, float* f){
  f[0]=u2f(v.x<<16); f[1]=u2f(v.x&0xFFFF0000u);
  f[2]=u2f(v.y<<16); f[3]=u2f(v.y&0xFFFF0000u);
  f[4]=u2f(v.z<<16); f[5]=u2f(v.z&0xFFFF0000u);
  f[6]=u2f(v.w<<16); f[7]=u2f(v.w&0xFFFF0000u);
}

// ---------------------------------------------------------------------------
// Convert 11 f32 weight matrices (MFMA B-operands) to bf16; zero CSR degrees.
// Order: wih0,whh0,wih1,whh1, wl0,wr0,pw0, wl1,wr1,pw1 (65536 ea), mow0 (16384).
// Uniform source select on blockIdx.x>>8 (no runtime-indexed pointer array).
// ---------------------------------------------------------------------------
__global__ __launch_bounds__(256) void conv_w_k(
    const float* s0, const float* s1, const float* s2, const float* s3,
    const float* s4, const float* s5, const float* s6, const float* s7,
    const float* s8, const float* s9, const float* s10,
    bf16* __restrict__ dst, int* __restrict__ deg)
{
  int idx = blockIdx.x*256 + threadIdx.x;
  if (idx < NNODES) deg[idx] = 0;
  if (idx >= 671744) return;
  int b = blockIdx.x >> 8;        // uniform per block: 0..9 chunks, 10 = mow0
  const float* s;
  if      (b == 0) s = s0;
  else if (b == 1) s = s1;
  else if (b == 2) s = s2;
  else if (b == 3) s = s3;
  else if (b == 4) s = s4;
  else if (b == 5) s = s5;
  else if (b == 6) s = s6;
  else if (b == 7) s = s7;
  else if (b == 8) s = s8;
  else if (b == 9) s = s9;
  else             s = s10;
  dst[idx] = __float2bfloat16(s[idx - b*65536]);
}

// ---------------------------------------------------------------------------
// Prep + MERGED deg-count (deg zeroed by conv_w_k, stream-ordered before us):
// blocks 0..7: Wp fold. block 8: bp, bsum, gblr. 9..: degree atomics.
// ---------------------------------------------------------------------------
__global__ __launch_bounds__(256) void prep_w_k(
    const float* __restrict__ miw0, const float* __restrict__ mib0,
    const float* __restrict__ miw1, const float* __restrict__ mib1,
    const float* __restrict__ bih0, const float* __restrict__ bhh0,
    const float* __restrict__ bih1, const float* __restrict__ bhh1,
    const float* __restrict__ bl0, const float* __restrict__ br0,
    const float* __restrict__ bl1, const float* __restrict__ br1,
    float* __restrict__ Wp, float* __restrict__ bp,
    float* __restrict__ bsum, float* __restrict__ gblr,
    const int* __restrict__ dst, int* __restrict__ deg, int E)
{
  int t = threadIdx.x;
  int b = blockIdx.x;
  if (b >= 9){
    int e = (b-9)*256 + t;
    if (e < E){
      unsigned d = (unsigned)dst[e];
      if (d < (unsigned)NNODES) atomicAdd(&deg[d], 1);
    }
    return;
  }
  if (b < 8){
    int idx = b*256 + t;          // < 2048 = HID*INDIM
    int j = idx >> 4, d = idx & 15;
    float s = 0.f;
    for (int k=0;k<HID;k++) s += miw1[j*HID+k] * miw0[k*INDIM+d];
    Wp[idx] = s;
    return;
  }
  // block 8: bp + bsum + gblr
  if (t < HID){
    float s = mib1[t];
    for (int k=0;k<HID;k++) s += miw1[t*HID+k] * mib0[k];
    bp[t] = s;
  }
  for (int i = t; i < GDIM; i += 256){
    bsum[i]        = bih0[i] + bhh0[i];
    bsum[GDIM + i] = bih1[i] + bhh1[i];
  }
  for (int i = t; i < GDIM; i += 256){
    gblr[i]          = bl0[i];
    gblr[GDIM + i]   = br0[i];
    gblr[1024 + i]   = bl1[i];
    gblr[1536 + i]   = br1[i];
  }
}

// ---------------------------------------------------------------------------
// PARALLEL exclusive scan: 1024 threads x 10 elems, wave shfl-scan + 16
// wave-sums. Integer-exact => CSR identical.
// ---------------------------------------------------------------------------
__global__ __launch_bounds__(1024) void scan_k(
    const int* __restrict__ deg, int* __restrict__ offs,
    int* __restrict__ cursor, int n)
{
  __shared__ int wsum[16];
  __shared__ int wpre[16];
  const int t = threadIdx.x;
  const int lane = t & 63, wv = t >> 6;
  const int lo = t*10;
  int loc[10];
  int s = 0;
  #pragma unroll
  for (int i=0;i<10;i++){
    int idx = lo + i;
    int d = (idx < n) ? deg[idx] : 0;
    loc[i] = d; s += d;
  }
  int sc = s;
  #pragma unroll
  for (int off=1; off<64; off<<=1){
    int u = __shfl_up(sc, off);
    if (lane >= off) sc += u;
  }
  if (lane == 63) wsum[wv] = sc;
  __syncthreads();
  if (t == 0){
    int run = 0;
    #pragma unroll
    for (int i=0;i<16;i++){ wpre[i] = run; run += wsum[i]; }
    offs[n] = run;
  }
  __syncthreads();
  int run = wpre[wv] + (sc - s);   // exclusive prefix for this thread
  #pragma unroll
  for (int i=0;i<10;i++){
    int idx = lo + i;
    if (idx < n){ offs[idx] = run; cursor[idx] = run; run += loc[i]; }
  }
}

// ---------------------------------------------------------------------------
// MLP-in + MERGED CSR fill (scan_k runs before this dispatch).
// Grid 3750 x 256 = 960000 threads >= E.
// ---------------------------------------------------------------------------
__global__ __launch_bounds__(256) void mlp_in_k(
    const float* __restrict__ x, const float* __restrict__ Wp,
    const float* __restrict__ bp, bf16* __restrict__ X0,
    const int* __restrict__ srcp, const int* __restrict__ dstp,
    int* __restrict__ curs, int* __restrict__ srcs, int E)
{
  __shared__ __align__(16) float xs[64*16];
  const int tid = threadIdx.x;
  const int m0 = blockIdx.x*64;
  {
    int row = tid >> 2, q = tid & 3;
    int m = m0 + row;
    int t = m / NNODES, n = m - t*NNODES;
    float4 v = *(const float4*)(x + ((size_t)n*TLEN + t)*INDIM + q*4);
    *(float4*)(xs + row*16 + q*4) = v;
  }
  {
    int gid = blockIdx.x*256 + tid;
    if (gid < E){
      unsigned d = (unsigned)dstp[gid];
      if (d < (unsigned)NNODES){
        int p = atomicAdd(&curs[d], 1);
        unsigned s = (unsigned)srcp[gid];
        srcs[p] = (s < (unsigned)NNODES) ? (int)s : 0;
      }
    }
  }
  const int j = tid & 127;
  const int half = tid >> 7;
  const float* wr = Wp + j*INDIM;
  float4 w0 = *(const float4*)(wr);
  float4 w1 = *(const float4*)(wr + 4);
  float4 w2 = *(const float4*)(wr + 8);
  float4 w3 = *(const float4*)(wr + 12);
  float bj = bp[j];
  __syncthreads();
  #pragma unroll 4
  for (int mi=0; mi<32; mi++){
    int row = mi*2 + half;
    const float* xr = xs + row*16;
    float4 a0 = *(const float4*)(xr);
    float4 a1 = *(const float4*)(xr + 4);
    float4 a2 = *(const float4*)(xr + 8);
    float4 a3 = *(const float4*)(xr + 12);
    float s = bj
      + a0.x*w0.x + a0.y*w0.y + a0.z*w0.z + a0.w*w0.w
      + a1.x*w1.x + a1.y*w1.y + a1.z*w1.z + a1.w*w1.w
      + a2.x*w2.x + a2.y*w2.y + a2.z*w2.z + a2.w*w2.w
      + a3.x*w3.x + a3.y*w3.y + a3.z*w3.z + a3.w*w3.w;
    s = s > 0.f ? s : 0.f;
    X0[(size_t)(m0+row)*HID + j] = __float2bfloat16(s);
  }
}

// ---------------------------------------------------------------------------
// LSTM layer body (proven M=48 structure, merged 8-trans epilogue).
// Called twice from lstm_f2 — layer 0 (WRITE_ALL=1) writes h(t) in-place over
// Xio; layer 1 (WRITE_ALL=0) reads them back (same thread, same addresses;
// the inter-layer __syncthreads drains vmcnt) and writes final h to out.
// ---------------------------------------------------------------------------
template<int WRITE_ALL>
__device__ __forceinline__ void lstm_layer(
    bf16* Xio, const bf16* __restrict__ Wih, const bf16* __restrict__ Whh,
    const float* __restrict__ bias, bf16* __restrict__ out,
    bf16* hs, bf16* xs, int m0)
{
  const int tid = threadIdx.x;
  const int lane = tid & 63, w = tid >> 6;
  const int r16 = lane & 15, quad = lane >> 4;
  const int HB = 48*136;   // one buffer

  v8s wbi[4][4], wbh[4][4];
  #pragma unroll
  for (int g=0; g<4; g++)
    #pragma unroll
    for (int kc=0; kc<4; kc++){
      size_t o = (size_t)(g*HID + w*16 + r16)*HID + kc*32 + quad*8;
      wbi[g][kc] = *(const v8s*)(Wih + o);
      wbh[g][kc] = *(const v8s*)(Whh + o);
    }
  float bg[4];
  #pragma unroll
  for (int g=0; g<4; g++) bg[g] = bias[g*HID + w*16 + r16];

  const int row0 = tid >> 4;                 // rows 0..31
  const int c8   = (tid & 15) * 8;
  const int row1 = 32 + (tid >> 4);          // rows 32..47 (tid < 256 only)
  const int gr0 = m0 + row0;
  const int gr1 = m0 + row1;
  const int gr0c = gr0 < NNODES ? gr0 : NNODES-1;
  const int gr1c = gr1 < NNODES ? gr1 : NNODES-1;
  const bf16* ldp0 = Xio + (size_t)gr0c*HID + c8;
  const bf16* ldp1 = Xio + (size_t)gr1c*HID + c8;
  bf16* stp0 = Xio + (size_t)gr0*HID + c8;
  bf16* stp1 = Xio + (size_t)gr1*HID + c8;
  const size_t TS = (size_t)NNODES*HID;

  for (int i = tid; i < 816; i += 512)
    *(uint4*)((char*)hs + i*16) = make_uint4(0,0,0,0);   // zero hs[0]

  {
    uint4 a = *(const uint4*)ldp0;
    *(uint4*)(xs + row0*136 + c8) = a;
    if (tid < 256){
      uint4 b = *(const uint4*)ldp1;
      *(uint4*)(xs + row1*136 + c8) = b;
    }
  }
  __syncthreads();

  float c[3][4];
  #pragma unroll
  for (int tl=0; tl<3; tl++)
    #pragma unroll
    for (int r=0; r<4; r++) c[tl][r] = 0.f;

  const int fb = r16*136 + quad*8;   // frag base within a 16-row tile

  #pragma unroll 1
  for (int t=0; t<TLEN; t++){
    const int cur = t & 1, nxt = cur ^ 1;
    const bf16* xrd = xs + cur*HB;
    const bf16* hrd = hs + cur*HB;
    bf16* hwr = hs + nxt*HB;

    const int tn = (t+1 < TLEN) ? t+1 : TLEN-1;
    uint4 xa = *(const uint4*)(ldp0 + (size_t)tn*TS);
    uint4 xb;
    if (tid < 256) xb = *(const uint4*)(ldp1 + (size_t)tn*TS);

    #pragma unroll
    for (int tl=0; tl<3; tl++){
      v4f acc[4];
      #pragma unroll
      for (int g=0; g<4; g++) acc[g] = (v4f)0.f;

      #pragma unroll
      for (int kc=0; kc<4; kc++){
        v8s av = *(const v8s*)(xrd + tl*2176 + fb + kc*32);
        #pragma unroll
        for (int g=0; g<4; g++)
          acc[g] = __builtin_amdgcn_mfma_f32_16x16x32_bf16(av, wbi[g][kc], acc[g], 0, 0, 0);
      }
      #pragma unroll
      for (int kc=0; kc<4; kc++){
        v8s hv = *(const v8s*)(hrd + tl*2176 + fb + kc*32);
        #pragma unroll
        for (int g=0; g<4; g++)
          acc[g] = __builtin_amdgcn_mfma_f32_16x16x32_bf16(hv, wbh[g][kc], acc[g], 0, 0, 0);
      }

      #pragma unroll
      for (int r=0; r<4; r++){
        float iv = acc[0][r] + bg[0];
        float fv = acc[1][r] + bg[1];
        float gv = acc[2][r] + bg[2];
        float ov = acc[3][r] + bg[3];
        float sf = frcp(1.f + __expf(-fv));
        float ei = __expf(-iv);
        float tg = __expf(-2.f*fabsf(gv));
        float itg = copysignf((1.f - tg)*frcp((1.f + ei)*(1.f + tg)), gv);
        float cn = sf*c[tl][r] + itg;
        c[tl][r] = cn;
        float eo = __expf(-ov);
        float tc = __expf(-2.f*fabsf(cn));
        float hh = copysignf((1.f - tc)*frcp((1.f + eo)*(1.f + tc)), cn);
        hwr[(tl*16 + quad*4 + r)*136 + w*16 + r16] = __float2bfloat16(hh);
      }
    }

    *(uint4*)(xs + nxt*HB + row0*136 + c8) = xa;
    if (tid < 256) *(uint4*)(xs + nxt*HB + row1*136 + c8) = xb;

    __syncthreads();

    if (WRITE_ALL){
      uint4 h0 = *(const uint4*)(hwr + row0*136 + c8);
      if (gr0 < NNODES) *(uint4*)(stp0 + (size_t)t*TS) = h0;
      if (tid < 256){
        uint4 h1v = *(const uint4*)(hwr + row1*136 + c8);
        if (gr1 < NNODES) *(uint4*)(stp1 + (size_t)t*TS) = h1v;
      }
    }
  }

  if (!WRITE_ALL){
    const bf16* hf = hs + (TLEN & 1)*HB;
    uint4 h0 = *(const uint4*)(hf + row0*136 + c8);
    if (gr0 < NNODES) *(uint4*)(out + (size_t)gr0*HID + c8) = h0;
    if (tid < 256){
      uint4 h1v = *(const uint4*)(hf + row1*136 + c8);
      if (gr1 < NNODES) *(uint4*)(out + (size_t)gr1*HID + c8) = h1v;
    }
  }
}

// Fused 2-layer LSTM: one dispatch, both layers on the same 48-row tile.
__global__ __launch_bounds__(512) void lstm_f2(
    bf16* X0, const bf16* __restrict__ wih0, const bf16* __restrict__ whh0,
    const bf16* __restrict__ wih1, const bf16* __restrict__ whh1,
    const float* __restrict__ bsum, bf16* __restrict__ zf)
{
  __shared__ __align__(16) bf16 hs[2][48*136];
  __shared__ __align__(16) bf16 xs[2][48*136];
  const int m0 = blockIdx.x*48;
  lstm_layer<1>(X0, wih0, whh0, bsum,        nullptr, &hs[0][0], &xs[0][0], m0);
  __syncthreads();   // drain layer-0 final writeback before hs/xs reuse
  lstm_layer<0>(X0, wih1, whh1, bsum + GDIM, zf,      &hs[0][0], &xs[0][0], m0);
}

// ---------------------------------------------------------------------------
// Generic bf16 GEMM: C[M,N] = act(A[M,K] @ B[N,K]^T + bias_f32[N]), bf16 out.
// (Proven 128x128 tile.)
// ---------------------------------------------------------------------------
template<int ACT>
__global__ __launch_bounds__(256) void gemm_bt(
    const bf16* __restrict__ A, const bf16* __restrict__ B,
    const float* __restrict__ bias, bf16* __restrict__ C,
    int M, int N, int K)
{
  __shared__ __align__(16) bf16 As[128*40];
  __shared__ __align__(16) bf16 Bs[128*40];
  const int tid = threadIdx.x;
  const int m0 = blockIdx.x*128, n0 = blockIdx.y*128;
  const int lane = tid & 63, wave = tid >> 6;
  const int r16 = lane & 15, quad = lane >> 4;

  v4f acc[2][8];
  #pragma unroll
  for (int a=0;a<2;a++)
    #pragma unroll
    for (int b=0;b<8;b++) acc[a][b] = (v4f)0.f;

  for (int k0=0; k0<K; k0+=32){
    #pragma unroll
    for (int i=0;i<2;i++){
      int li = tid + i*256;
      int row = li >> 2, q4 = li & 3;
      uint4 va = make_uint4(0,0,0,0);
      int gm = m0 + row;
      if (gm < M) va = *(const uint4*)(A + (size_t)gm*K + k0 + q4*8);
      *(uint4*)(As + row*40 + q4*8) = va;
      uint4 vb = make_uint4(0,0,0,0);
      int gn = n0 + row;
      if (gn < N) vb = *(const uint4*)(B + (size_t)gn*K + k0 + q4*8);
      *(uint4*)(Bs + row*40 + q4*8) = vb;
    }
    __syncthreads();
    v8s av[2], bv[8];
    #pragma unroll
    for (int mi=0;mi<2;mi++)
      av[mi] = *(const v8s*)(As + (wave*32 + mi*16 + r16)*40 + quad*8);
    #pragma unroll
    for (int ni=0;ni<8;ni++)
      bv[ni] = *(const v8s*)(Bs + (ni*16 + r16)*40 + quad*8);
    #pragma unroll
    for (int mi=0;mi<2;mi++)
      #pragma unroll
      for (int ni=0;ni<8;ni++)
        acc[mi][ni] = __builtin_amdgcn_mfma_f32_16x16x32_bf16(av[mi], bv[ni], acc[mi][ni], 0, 0, 0);
    __syncthreads();
  }

  #pragma unroll
  for (int mi=0;mi<2;mi++){
    #pragma unroll
    for (int r=0;r<4;r++){
      int row = m0 + wave*32 + mi*16 + quad*4 + r;
      if (row >= M) continue;
      #pragma unroll
      for (int ni=0;ni<8;ni++){
        int col = n0 + ni*16 + r16;
        float v = acc[mi][ni][r] + bias[col];
        if (ACT == 1) v = v > 0.f ? v : 0.f;
        C[(size_t)row*N + col] = __float2bfloat16(v);
      }
    }
  }
}

// ---------------------------------------------------------------------------
// 64-row-tile GEMM for N=128 outputs (GAT projection).
// ---------------------------------------------------------------------------
template<int ACT>
__global__ __launch_bounds__(256) void gemm_bt64(
    const bf16* __restrict__ A, const bf16* __restrict__ B,
    const float* __restrict__ bias, bf16* __restrict__ C,
    int M, int K)   // N == 128
{
  __shared__ __align__(16) bf16 As[64*40];
  __shared__ __align__(16) bf16 Bs[128*40];
  const int tid = threadIdx.x;
  const int m0 = blockIdx.x*64;
  const int lane = tid & 63, wave = tid >> 6;
  const int r16 = lane & 15, quad = lane >> 4;

  v4f acc[8];
  #pragma unroll
  for (int b=0;b<8;b++) acc[b] = (v4f)0.f;

  for (int k0=0; k0<K; k0+=32){
    {
      int row = tid >> 2, q4 = tid & 3;
      uint4 va = make_uint4(0,0,0,0);
      int gm = m0 + row;
      if (gm < M) va = *(const uint4*)(A + (size_t)gm*K + k0 + q4*8);
      *(uint4*)(As + row*40 + q4*8) = va;
    }
    #pragma unroll
    for (int i=0;i<2;i++){
      int li = tid + i*256;
      int row = li >> 2, q4 = li & 3;
      uint4 vb = *(const uint4*)(B + (size_t)row*K + k0 + q4*8);
      *(uint4*)(Bs + row*40 + q4*8) = vb;
    }
    __syncthreads();
    v8s av, bv[8];
    av = *(const v8s*)(As + (wave*16 + r16)*40 + quad*8);
    #pragma unroll
    for (int ni=0;ni<8;ni++)
      bv[ni] = *(const v8s*)(Bs + (ni*16 + r16)*40 + quad*8);
    #pragma unroll
    for (int ni=0;ni<8;ni++)
      acc[ni] = __builtin_amdgcn_mfma_f32_16x16x32_bf16(av, bv[ni], acc[ni], 0, 0, 0);
    __syncthreads();
  }

  #pragma unroll
  for (int r=0;r<4;r++){
    int row = m0 + wave*16 + quad*4 + r;
    if (row >= M) continue;
    #pragma unroll
    for (int ni=0;ni<8;ni++){
      int col = ni*16 + r16;
      float v = acc[ni][r] + bias[col];
      if (ACT == 1) v = v > 0.f ? v : 0.f;
      C[(size_t)row*HID + col] = __float2bfloat16(v);
    }
  }
}

// ---------------------------------------------------------------------------
// MLP-out FUSED: o0 = relu(z3 @ mow0^T + mob0) like gemm_bt64, o0 tile to
// LDS, then the final N=24 layer from LDS (same accumulation order).
// ---------------------------------------------------------------------------
__global__ __launch_bounds__(256) void mlp_out_fused_k(
    const bf16* __restrict__ A, const bf16* __restrict__ B,
    const float* __restrict__ bias, const float* __restrict__ w1,
    const float* __restrict__ b1, float* __restrict__ out, int M)
{
  __shared__ __align__(16) bf16 As[64*40];
  __shared__ __align__(16) bf16 Bs[128*40];
  __shared__ __align__(16) bf16 o0s[64*136];
  const int tid = threadIdx.x;
  const int m0 = blockIdx.x*64;
  const int lane = tid & 63, wave = tid >> 6;
  const int r16 = lane & 15, quad = lane >> 4;

  v4f acc[8];
  #pragma unroll
  for (int b=0;b<8;b++) acc[b] = (v4f)0.f;

  for (int k0=0; k0<HID; k0+=32){
    {
      int row = tid >> 2, q4 = tid & 3;
      uint4 va = make_uint4(0,0,0,0);
      int gm = m0 + row;
      if (gm < M) va = *(const uint4*)(A + (size_t)gm*HID + k0 + q4*8);
      *(uint4*)(As + row*40 + q4*8) = va;
    }
    #pragma unroll
    for (int i=0;i<2;i++){
      int li = tid + i*256;
      int row = li >> 2, q4 = li & 3;
      uint4 vb = *(const uint4*)(B + (size_t)row*HID + k0 + q4*8);
      *(uint4*)(Bs + row*40 + q4*8) = vb;
    }
    __syncthreads();
    v8s av, bv[8];
    av = *(const v8s*)(As + (wave*16 + r16)*40 + quad*8);
    #pragma unroll
    for (int ni=0;ni<8;ni++)
      bv[ni] = *(const v8s*)(Bs + (ni*16 + r16)*40 + quad*8);
    #pragma unroll
    for (int ni=0;ni<8;ni++)
      acc[ni] = __builtin_amdgcn_mfma_f32_16x16x32_bf16(av, bv[ni], acc[ni], 0, 0, 0);
    __syncthreads();
  }

  #pragma unroll
  for (int r=0;r<4;r++){
    int row = wave*16 + quad*4 + r;
    #pragma unroll
    for (int ni=0;ni<8;ni++){
      int col = ni*16 + r16;
      float v = acc[ni][r] + bias[col];
      v = v > 0.f ? v : 0.f;
      o0s[row*136 + col] = __float2bfloat16(v);
    }
  }
  __syncthreads();

  for (int idx = tid; idx < 64*24; idx += 256){
    int row = idx / 24, j = idx - row*24;
    if (m0 + row >= M) continue;
    const bf16* ar = o0s + row*136;
    const float* wr = w1 + j*HID;
    float s = b1[j];
    for (int k=0;k<HID;k+=8){
      float fa[8];
      unpack8(*(const uint4*)(ar+k), fa);
      float4 w0 = *(const float4*)(wr + k);
      float4 w1v = *(const float4*)(wr + k + 4);
      s += fa[0]*w0.x + fa[1]*w0.y + fa[2]*w0.z + fa[3]*w0.w
         + fa[4]*w1v.x + fa[5]*w1v.y + fa[6]*w1v.z + fa[7]*w1v.w;
    }
    out[(size_t)(m0+row)*24 + j] = s;
  }
}

// ---------------------------------------------------------------------------
// GATv2 online-softmax fused score+aggregate, distance-2 prefetch pipeline
// (order-identical math). 1 wave/dst node.
// ---------------------------------------------------------------------------
__global__ __launch_bounds__(256) void gat_onl(
    const int* __restrict__ offs, const int* __restrict__ srcs,
    const bf16* __restrict__ xc, const float* __restrict__ att,
    const float* __restrict__ gbias, bf16* __restrict__ agg)
{
  int d = blockIdx.x*4 + (threadIdx.x >> 6);
  if (d >= NNODES) return;
  int lane = threadIdx.x & 63;
  float fr[8];
  unpack8(*(const uint4*)(xc + (size_t)d*1024 + 512 + lane*8), fr);
  float4 a0 = *(const float4*)(att + lane*8);
  float4 a1 = *(const float4*)(att + lane*8 + 4);
  float fa[8] = {a0.x,a0.y,a0.z,a0.w,a1.x,a1.y,a1.z,a1.w};
  int i0 = offs[d], i1 = offs[d+1];

  float m = -3.4e38f, den = 0.f;
  float acc[8] = {0,0,0,0,0,0,0,0};

  if (i0 < i1){
    uint4 r0 = *(const uint4*)(xc + (size_t)srcs[i0]*1024 + lane*8);
    uint4 r1 = r0;
    if (i0+1 < i1) r1 = *(const uint4*)(xc + (size_t)srcs[i0+1]*1024 + lane*8);
    for (int i=i0; i<i1; i++){
      uint4 r2 = r1;
      if (i+2 < i1) r2 = *(const uint4*)(xc + (size_t)srcs[i+2]*1024 + lane*8);
      float fl[8];
      unpack8(r0, fl);
      float p = 0.f;
      #pragma unroll
      for (int q=0;q<8;q++){
        float v = fl[q] + fr[q];
        v = v > 0.f ? v : 0.2f*v;
        p += v*fa[q];
      }
      p += __shfl_xor(p, 1); p += __shfl_xor(p, 2);
      p += __shfl_xor(p, 4); p += __shfl_xor(p, 8);
      float mn = fmaxf(m, p);
      float corr = __expf(m - mn);
      float w = __expf(p - mn);
      den = den*corr + w;
      #pragma unroll
      for (int q=0;q<8;q++) acc[q] = acc[q]*corr + w*fl[q];
      m = mn;
      r0 = r1; r1 = r2;
    }
  }
  float r = 1.f/(den + 1e-16f);
  float4 b0 = *(const float4*)(gbias + lane*8);
  float4 b1 = *(const float4*)(gbias + lane*8 + 4);
  float fb[8] = {b0.x,b0.y,b0.z,b0.w,b1.x,b1.y,b1.z,b1.w};
  #pragma unroll
  for (int q=0;q<8;q++)
    agg[(size_t)d*GDIM + lane*8 + q] = __float2bfloat16(acc[q]*r + fb[q]);
}

// ---------------------------------------------------------------------------

extern "C" void kernel_launch(void* const* d_in, const int* in_sizes, int n_in,
                              void* d_out, int out_size, void* d_ws, size_t ws_size,
                              hipStream_t stream)
{
  const float* x   = (const float*)d_in[0];
  const int*   ei  = (const int*)d_in[1];
  const int E = in_sizes[1] / 2;
  const int* srcp = ei;
  const int* dstp = ei + E;

  const float* miw0 = (const float*)d_in[2];
  const float* mib0 = (const float*)d_in[3];
  const float* miw1 = (const float*)d_in[4];
  const float* mib1 = (const float*)d_in[5];
  const float* wih0 = (const float*)d_in[6];
  const float* whh0 = (const float*)d_in[7];
  const float* bih0 = (const float*)d_in[8];
  const float* bhh0 = (const float*)d_in[9];
  const float* wih1 = (const float*)d_in[10];
  const float* whh1 = (const float*)d_in[11];
  const float* bih1 = (const float*)d_in[12];
  const float* bhh1 = (const float*)d_in[13];
  const float* g_wl[2]   = {(const float*)d_in[14], (const float*)d_in[22]};
  const float* g_bl[2]   = {(const float*)d_in[15], (const float*)d_in[23]};
  const float* g_wr[2]   = {(const float*)d_in[16], (const float*)d_in[24]};
  const float* g_br[2]   = {(const float*)d_in[17], (const float*)d_in[25]};
  const float* g_att[2]  = {(const float*)d_in[18], (const float*)d_in[26]};
  const float* g_bias[2] = {(const float*)d_in[19], (const float*)d_in[27]};
  const float* g_pw[2]   = {(const float*)d_in[20], (const float*)d_in[28]};
  const float* g_pb[2]   = {(const float*)d_in[21], (const float*)d_in[29]};
  const float* mow0 = (const float*)d_in[30];
  const float* mob0 = (const float*)d_in[31];
  const float* mow1 = (const float*)d_in[32];
  const float* mob1 = (const float*)d_in[33];
  (void)n_in; (void)out_size; (void)ws_size;

  // ---- workspace layout ----
  char* base = (char*)d_ws;
  size_t off = 0;
  auto carve = [&](size_t n)->char*{
    char* p = base + off;
    off = (off + n + 255) & ~(size_t)255;
    return p;
  };
  char*  X0r = carve((size_t)TLEN*NNODES*HID*2);   // 61,440,000
  bf16*  zf  = (bf16*)carve((size_t)NNODES*HID*2);
  float* Wp  = (float*)carve(HID*INDIM*4);
  float* bp  = (float*)carve(HID*4);
  float* bsum= (float*)carve(2*GDIM*4);
  float* gblr= (float*)carve(2*1024*4);
  bf16*  wbf = (bf16*)carve((size_t)671744*2);
  int*   offsb = (int*)carve((size_t)(NNODES+1)*4);
  int*   curs  = (int*)carve((size_t)NNODES*4);
  int*   srcs  = (int*)carve((size_t)E*4);
  int*   deg   = (int*)carve((size_t)NNODES*4);
  bf16*  agg   = (bf16*)carve((size_t)NNODES*GDIM*2);

  // wbf sub-pointers (conv_w_k chunk order)
  const bf16* wih0b = wbf + 0;
  const bf16* whh0b = wbf + 65536;
  const bf16* wih1b = wbf + 131072;
  const bf16* whh1b = wbf + 196608;
  const bf16* wlr0b = wbf + 262144;   // wl0|wr0 contiguous [1024,128]
  const bf16* pw0b  = wbf + 393216;
  const bf16* wlr1b = wbf + 458752;   // wl1|wr1 contiguous
  const bf16* pw1b  = wbf + 589824;
  const bf16* mow0b = wbf + 655360;
  const bf16* wlrb[2] = {wlr0b, wlr1b};
  const bf16* pwb[2]  = {pw0b, pw1b};

  // X0 region aliases (holds X0, then h1 in-place, dead after LSTM)
  bf16* X0 = (bf16*)X0r;
  bf16* xc = (bf16*)X0r;                      // [10000,1024] = xl|xr
  bf16* z2 = (bf16*)(X0r + 20480000);
  bf16* z3 = (bf16*)(X0r + 23040000);

  // ---- prep: conv (zeroes deg) -> prep(+deg count) -> scan ----
  conv_w_k<<<2624, 256, 0, stream>>>(wih0, whh0, wih1, whh1,
                                     g_wl[0], g_wr[0], g_pw[0],
                                     g_wl[1], g_wr[1], g_pw[1], mow0, wbf, deg);
  prep_w_k<<<9 + (E+255)/256, 256, 0, stream>>>(miw0, mib0, miw1, mib1,
                                  bih0, bhh0, bih1, bhh1,
                                  g_bl[0], g_br[0], g_bl[1], g_br[1],
                                  Wp, bp, bsum, gblr, dstp, deg, E);
  scan_k<<<1, 1024, 0, stream>>>(deg, offsb, curs, NNODES);

  // ---- MLP in (+ merged CSR fill) ----
  mlp_in_k<<<(TLEN*NNODES)/64, 256, 0, stream>>>(x, Wp, bp, X0,
                                                 srcp, dstp, curs, srcs, E);

  // ---- LSTM: both layers fused, one dispatch, 209 blocks x 512 threads ----
  const int NBL48 = (NNODES + 47) / 48;   // 209
  lstm_f2<<<NBL48, 512, 0, stream>>>(X0, wih0b, whh0b, wih1b, whh1b, bsum, zf);

  // ---- GAT layers ----
  const bf16* zin = zf;
  bf16* zouts[2] = {z2, z3};
  const int NB64 = (NNODES + 63) / 64;   // 157 blocks
  for (int l=0; l<2; l++){
    gemm_bt<0><<<dim3(79,8), 256, 0, stream>>>(zin, wlrb[l], gblr + l*1024, xc, NNODES, 1024, HID);
    gat_onl<<<(NNODES+3)/4, 256, 0, stream>>>(offsb, srcs, xc, g_att[l], g_bias[l], agg);
    gemm_bt64<1><<<NB64, 256, 0, stream>>>(agg, pwb[l], g_pb[l], zouts[l], NNODES, GDIM);
    zin = zouts[l];
  }

  // ---- MLP out (fused GEMM + final layer) ----
  mlp_out_fused_k<<<NB64, 256, 0, stream>>>(z3, mow0b, mob0, mow1, mob1,
                                            (float*)d_out, NNODES);
}